// Round 1
// baseline (1180.970 us; speedup 1.0000x reference)
//
#include <hip/hip_runtime.h>

// Sinkhorn, fully fused: 2 dispatches total.
//   k_build: KT = exp(-20*C)^T (fp32, LDS tile transpose) + state init.
//   k_loop : persistent kernel, 128 blocks x 512 thr (<= half the CUs ->
//            co-residency guaranteed by capacity; no cooperative launch).
//            Each wave owns TWO rows of K and TWO cols of K in VGPRs
//            (fp32, 128 regs/lane; the whole 33 MB matrix sits in the
//            register file across 2048 waves) -> zero matrix traffic in
//            the 100 half-steps. Device-wide monotonic-counter barrier
//            (agent-scope atomics + __threadfence for cross-XCD L2
//            coherence) between half-steps. Output epilogue fused at end.
// Math identical to the 104-dispatch version (absmax ~7.6e-6):
//   z_j = e^{v_j/eps}, w_i = e^{u_i/eps}, K = exp(-20C) fp32, state fp64.
//   row:  w_i = (1/4096)/(sum_j K_ij z_j + 2048*zpad)
//   col:  z_j = (1/4096)/(sum_i K^T_ji w_i + 2048*wpad)
//   pads: wpad = (1/4096)/(sum_j z_j + 2048*zpad); zpad symmetric.

#define INV_N (1.0 / 4096.0)
#define NBLK 128u

// ---- scratch layout inside d_out (67,108,864 bytes) ----
#define OFF_KT 0UL            // KT fp32 2048x2048 -> overwritten by out rows 0..1023 in epilogue
#define OFF_W 67059712UL      // w: 2048 fp64 = out row 4093
#define OFF_Z 67076096UL      // z: 2048 fp64 = out row 4094
#define OFF_SCAL 67092480UL   // scal[0]=wpad scal[1]=zpad (out row 4095)
#define OFF_SWB 67092544UL    // 128 fp64 per-block sums of w
#define OFF_SZB 67094592UL    // 128 fp64 per-block sums of z
#define OFF_CNT 67096640UL    // u32 barrier counter (zeroed by k_build each launch)

// fp64 exp (rel err ~3e-13 on [-20,0]).
static __device__ __forceinline__ double fexp(double x) {
  double t = x * 1.4426950408889634074;
  double n = rint(t);
  double r = fma(n, -0.69314718055994530942, x);
  double p = 2.7557319223985890653e-7;
  p = fma(p, r, 2.7557319223985890653e-6);
  p = fma(p, r, 2.4801587301587301587e-5);
  p = fma(p, r, 1.9841269841269841270e-4);
  p = fma(p, r, 1.3888888888888888889e-3);
  p = fma(p, r, 8.3333333333333333333e-3);
  p = fma(p, r, 4.1666666666666666667e-2);
  p = fma(p, r, 1.6666666666666666667e-1);
  p = fma(p, r, 0.5);
  p = fma(p, r, 1.0);
  p = fma(p, r, 1.0);
  long long bits = ((long long)(1023 + (int)n)) << 52;
  return p * __longlong_as_double(bits);
}

// Build KT (fp32, via LDS tile transpose) + init state + zero the barrier.
// 1024 blocks x 256 thr; one 64x64 tile per block.
__global__ __launch_bounds__(256) void k_build(const float* __restrict__ C, char* base) {
  float* KT = (float*)(base + OFF_KT);
  __shared__ float s_t[64][65];
  int b = blockIdx.x, tid = threadIdx.x;
  int ti = b >> 5, tj = b & 31;
  int r0 = tid >> 6, c = tid & 63;
#pragma unroll
  for (int k = 0; k < 16; ++k) {
    int r = r0 + 4 * k;
    int row = ti * 64 + r, col = tj * 64 + c;
    s_t[r][c] = (float)fexp(-20.0 * (double)C[(size_t)row * 2048 + col]);
  }
  __syncthreads();
#pragma unroll
  for (int k = 0; k < 16; ++k) {
    int r = r0 + 4 * k;
    KT[(size_t)(tj * 64 + r) * 2048 + ti * 64 + c] = s_t[c][r];
  }
  if (b == 0) {
    double* z = (double*)(base + OFF_Z);
    double* scal = (double*)(base + OFF_SCAL);
    double* SzB = (double*)(base + OFF_SZB);
    unsigned* cnt = (unsigned*)(base + OFF_CNT);
    for (int t = tid; t < 2048; t += 256) z[t] = 1.0;
    if (tid < 128) SzB[tid] = (tid == 0) ? 2048.0 : 0.0;
    if (tid == 0) { scal[1] = 1.0; *cnt = 0u; }
  }
}

// Device-wide barrier: monotonic counter, agent scope. __threadfence gives
// the buffer_wbl2/buffer_inv (sc1) needed so writes/reads cross XCD L2s.
static __device__ __forceinline__ void gsync(unsigned* cnt, unsigned target) {
  __syncthreads();              // all waves' stores drained (vmcnt 0) before arrival
  if (threadIdx.x == 0) {
    __threadfence();            // release: write back this XCD's L2
    __hip_atomic_fetch_add(cnt, 1u, __ATOMIC_RELAXED, __HIP_MEMORY_SCOPE_AGENT);
    while (__hip_atomic_load(cnt, __ATOMIC_RELAXED, __HIP_MEMORY_SCOPE_AGENT) < target)
      __builtin_amdgcn_s_sleep(2);
    __threadfence();            // acquire: invalidate stale L1/L2 lines
  }
  __syncthreads();
  asm volatile("" ::: "memory");  // keep compiler from hoisting loads above the barrier
}

// One half-step, 2 rows per wave. km[a,b] = this wave's two matrix rows in
// VGPRs (fp32 pairs, element j = 2*(l+64k)+{0,1}).
static __device__ __forceinline__ void half_phase(
    const float2 (&ka)[16], const float2 (&kb)[16], const double* __restrict__ vin,
    double* __restrict__ vout, const double* __restrict__ SpIn, double* __restrict__ SpOut,
    const double* padIn, double* padOut, double* s_v, double* s_w16,
    int tid, int b, int wv, int l, int i0, int i1) {
  const double2* vg = (const double2*)vin;
  ((double2*)s_v)[tid] = vg[tid];
  ((double2*)s_v)[tid + 512] = vg[tid + 512];
  // pad dual: atomic load -> guaranteed vector load, no stale scalar cache
  double pads = __hip_atomic_load((double*)padIn, __ATOMIC_RELAXED, __HIP_MEMORY_SCOPE_AGENT);
  __syncthreads();
  const double2* vz = (const double2*)s_v;
  double a0 = 0, a1 = 0, b0 = 0, b1 = 0;
#pragma unroll
  for (int k = 0; k < 16; ++k) {
    double2 p = vz[l + 64 * k];  // dense 16B/lane, conflict-free
    a0 = fma((double)ka[k].x, p.x, a0);
    a1 = fma((double)ka[k].y, p.y, a1);
    b0 = fma((double)kb[k].x, p.x, b0);
    b1 = fma((double)kb[k].y, p.y, b1);
  }
  double accA = a0 + a1, accB = b0 + b1;
#pragma unroll
  for (int off = 32; off; off >>= 1) {
    accA += __shfl_xor(accA, off, 64);
    accB += __shfl_xor(accB, off, 64);
  }
  double wiA = INV_N / (accA + 2048.0 * pads);
  double wiB = INV_N / (accB + 2048.0 * pads);
  if (l == 0) {
    vout[i0] = wiA; s_w16[wv] = wiA;
    vout[i1] = wiB; s_w16[8 + wv] = wiB;
  }
  if (b == 0 && wv == 7) {  // pad dual for the NEXT half-step (from prev partials)
    double tp = SpIn[l] + SpIn[l + 64];
#pragma unroll
    for (int off = 32; off; off >>= 1) tp += __shfl_xor(tp, off, 64);
    if (l == 0) *padOut = INV_N / (tp + 2048.0 * pads);
  }
  __syncthreads();
  if (tid == 0) {
    double s = 0;
#pragma unroll
    for (int q = 0; q < 16; ++q) s += s_w16[q];
    SpOut[b] = s;
  }
}

// Persistent kernel: reg-load -> 100 half-steps (device barriers) -> epilogue.
__global__ __launch_bounds__(512, 2) void k_loop(const float* __restrict__ C, char* base) {
  double* w = (double*)(base + OFF_W);
  double* z = (double*)(base + OFF_Z);
  double* scal = (double*)(base + OFF_SCAL);
  double* SwB = (double*)(base + OFF_SWB);
  double* SzB = (double*)(base + OFF_SZB);
  unsigned* cnt = (unsigned*)(base + OFF_CNT);
  const float* KT = (const float*)(base + OFF_KT);
  float* out = (float*)base;

  __shared__ double s_v[2048];
  __shared__ float s_valf[2048];
  __shared__ double s_w16[16];

  const int tid = threadIdx.x, b = blockIdx.x;
  const int wv = tid >> 6, l = tid & 63;
  const int i0 = b * 16 + wv, i1 = i0 + 8;

  // ---- pin K rows (from C, fp64 exp -> fp32) and K cols (from KT) in VGPRs ----
  float2 kra[16], krb[16], kca[16], kcb[16];
  {
    const float2* cA = (const float2*)(C + (size_t)i0 * 2048);
    const float2* cB = (const float2*)(C + (size_t)i1 * 2048);
    const float2* tA = (const float2*)(KT + (size_t)i0 * 2048);
    const float2* tB = (const float2*)(KT + (size_t)i1 * 2048);
#pragma unroll
    for (int k = 0; k < 16; ++k) {
      float2 ca = cA[l + 64 * k], cb = cB[l + 64 * k];
      kra[k].x = (float)fexp(-20.0 * (double)ca.x);
      kra[k].y = (float)fexp(-20.0 * (double)ca.y);
      krb[k].x = (float)fexp(-20.0 * (double)cb.x);
      krb[k].y = (float)fexp(-20.0 * (double)cb.y);
      kca[k] = tA[l + 64 * k];
      kcb[k] = tB[l + 64 * k];
    }
  }

  unsigned bar = 0;
  for (int t = 0; t < 50; ++t) {
    // row update: w from z (pad: wpad from sum(z), consumed next half-step)
    half_phase(kra, krb, z, w, SzB, SwB, scal + 1, scal + 0, s_v, s_w16, tid, b, wv, l, i0, i1);
    ++bar; gsync(cnt, NBLK * bar);
    // col update: z from w (pad: zpad from sum(w))
    half_phase(kca, kcb, w, z, SwB, SzB, scal + 0, scal + 1, s_v, s_w16, tid, b, wv, l, i0, i1);
    ++bar; gsync(cnt, NBLK * bar);
  }

  // ---- epilogue: stage final state, barrier, then materialize all 4096 rows ----
  {
    const double2* zg = (const double2*)z;
    double2 z0 = zg[tid], z1 = zg[tid + 512];
    ((double2*)s_v)[tid] = z0;
    ((double2*)s_v)[tid + 512] = z1;
    double wpad = __hip_atomic_load(&scal[0], __ATOMIC_RELAXED, __HIP_MEMORY_SCOPE_AGENT);
    double zpad = __hip_atomic_load(&scal[1], __ATOMIC_RELAXED, __HIP_MEMORY_SCOPE_AGENT);
    if (tid < 16) s_w16[tid] = w[b * 16 + tid];
    // bottom-row pattern (identical for every row 2048..4095)
    s_valf[2 * tid] = (float)(4096.0 * fmin(wpad * z0.x, 1.0));
    s_valf[2 * tid + 1] = (float)(4096.0 * fmin(wpad * z0.y, 1.0));
    s_valf[1024 + 2 * tid] = (float)(4096.0 * fmin(wpad * z1.x, 1.0));
    s_valf[1024 + 2 * tid + 1] = (float)(4096.0 * fmin(wpad * z1.y, 1.0));
    // Barrier: every block finished reading w/z/scal/cnt from global before
    // rows 4093..4095 (which alias them) get overwritten below.
    ++bar; gsync(cnt, NBLK * bar);

    const double2* vz = (const double2*)s_v;
    float cf = (float)(4096.0 * fmin(wpad * zpad, 1.0));
    float4 fcb; fcb.x = cf; fcb.y = cf; fcb.z = cf; fcb.w = cf;

#pragma unroll
    for (int rr = 0; rr < 2; ++rr) {
      const int i = rr ? i1 : i0;
      double wi = s_w16[rr ? (8 + wv) : wv];
      // top row i: left = 4096*min(w_i z_j exp(-20C_ij),1), right = const
      const float2* crow = (const float2*)(C + (size_t)i * 2048);
      float2* orow2 = (float2*)(out + (size_t)i * 4096);
#pragma unroll 4
      for (int k = 0; k < 16; ++k) {
        float2 cv = crow[l + 64 * k];
        double2 p = vz[l + 64 * k];
        float2 f;
        f.x = (float)(4096.0 * fmin(wi * p.x * fexp(-20.0 * (double)cv.x), 1.0));
        f.y = (float)(4096.0 * fmin(wi * p.y * fexp(-20.0 * (double)cv.y), 1.0));
        orow2[l + 64 * k] = f;
      }
      float cr = (float)(4096.0 * fmin(wi * zpad, 1.0));
      float4 fct; fct.x = cr; fct.y = cr; fct.z = cr; fct.w = cr;
      float* orow = out + (size_t)i * 4096;
#pragma unroll
      for (int k = 0; k < 8; ++k) ((float4*)(orow + 2048))[l + 64 * k] = fct;
      // bottom row 2048+i (covers 2048..4095 incl. the state-aliasing tail)
      float* brow = out + (size_t)(2048 + i) * 4096;
#pragma unroll
      for (int k = 0; k < 8; ++k) ((float4*)brow)[l + 64 * k] = ((const float4*)s_valf)[l + 64 * k];
#pragma unroll
      for (int k = 0; k < 8; ++k) ((float4*)(brow + 2048))[l + 64 * k] = fcb;
    }
  }
}

extern "C" void kernel_launch(void* const* d_in, const int* in_sizes, int n_in,
                              void* d_out, int out_size, void* d_ws, size_t ws_size,
                              hipStream_t stream) {
  (void)in_sizes; (void)n_in; (void)d_ws; (void)ws_size; (void)out_size;
  const float* C = (const float*)d_in[0];
  char* base = (char*)d_out;
  k_build<<<1024, 256, 0, stream>>>(C, base);
  k_loop<<<128, 512, 0, stream>>>(C, base);
}

// Round 2
// 853.522 us; speedup vs baseline: 1.3836x; 1.3836x over previous
//
#include <hip/hip_runtime.h>

// Sinkhorn, fully fused: 2 dispatches.
//   k_build: KT = exp(-20*C)^T (fp32, LDS tile transpose) + state init.
//   k_loop : persistent kernel, 128 blocks x 512 thr. Each wave owns TWO rows
//            of K and TWO cols of K in VGPRs (whole 33 MB matrix lives in the
//            register file across 2048 waves) -> zero matrix traffic in the
//            100 half-steps.
// Device-wide sync: FENCE-FREE monotonic-counter barrier. All cross-block
// data (w/z/SpB/pads/counter) moves through relaxed agent-scope atomics,
// which emit sc0/sc1 cache-bypass accesses straight to the coherent Infinity
// Cache -> no buffer_wbl2/buffer_inv L2 maintenance (that was 11us/barrier in
// the previous version). Ordering: __syncthreads drains each wave's vmcnt
// before the leader's arrival add; sc1 loads after the spin can't be stale.
// Math identical to the 104-dispatch version (absmax ~7.6e-6):
//   z_j = e^{v_j/eps}, w_i = e^{u_i/eps}, K = exp(-20C) fp32, state fp64.
//   row:  w_i = (1/4096)/(sum_j K_ij z_j + 2048*zpad)
//   col:  z_j = (1/4096)/(sum_i K^T_ji w_i + 2048*wpad)
//   pads: wpad = (1/4096)/(sum_j z_j + 2048*zpad); zpad symmetric.

#define INV_N (1.0 / 4096.0)
#define NBLK 128u

// ---- scratch layout inside d_out (67,108,864 bytes) ----
#define OFF_KT 0UL            // KT fp32 2048x2048 -> overwritten by out rows in epilogue
#define OFF_W 67059712UL      // w: 2048 fp64 = out row 4093
#define OFF_Z 67076096UL      // z: 2048 fp64 = out row 4094
#define OFF_SCAL 67092480UL   // scal[0]=wpad scal[1]=zpad (out row 4095)
#define OFF_SWB 67092544UL    // 128 fp64 per-block sums of w
#define OFF_SZB 67094592UL    // 128 fp64 per-block sums of z
#define OFF_CNT 67096640UL    // u32 barrier counter fallback (if no d_ws)

static __device__ __forceinline__ double aload(const double* p) {
  return __hip_atomic_load(p, __ATOMIC_RELAXED, __HIP_MEMORY_SCOPE_AGENT);
}
static __device__ __forceinline__ void astore(double* p, double v) {
  __hip_atomic_store(p, v, __ATOMIC_RELAXED, __HIP_MEMORY_SCOPE_AGENT);
}

// fp64 exp (rel err ~3e-13 on [-20,0]).
static __device__ __forceinline__ double fexp(double x) {
  double t = x * 1.4426950408889634074;
  double n = rint(t);
  double r = fma(n, -0.69314718055994530942, x);
  double p = 2.7557319223985890653e-7;
  p = fma(p, r, 2.7557319223985890653e-6);
  p = fma(p, r, 2.4801587301587301587e-5);
  p = fma(p, r, 1.9841269841269841270e-4);
  p = fma(p, r, 1.3888888888888888889e-3);
  p = fma(p, r, 8.3333333333333333333e-3);
  p = fma(p, r, 4.1666666666666666667e-2);
  p = fma(p, r, 1.6666666666666666667e-1);
  p = fma(p, r, 0.5);
  p = fma(p, r, 1.0);
  p = fma(p, r, 1.0);
  long long bits = ((long long)(1023 + (int)n)) << 52;
  return p * __longlong_as_double(bits);
}

// Build KT (fp32, LDS tile transpose) + init state + zero the barrier counter.
// 1024 blocks x 256 thr; one 64x64 tile per block.
__global__ __launch_bounds__(256) void k_build(const float* __restrict__ C, char* base,
                                               unsigned* __restrict__ cnt) {
  float* KT = (float*)(base + OFF_KT);
  __shared__ float s_t[64][65];
  int b = blockIdx.x, tid = threadIdx.x;
  int ti = b >> 5, tj = b & 31;
  int r0 = tid >> 6, c = tid & 63;
#pragma unroll
  for (int k = 0; k < 16; ++k) {
    int r = r0 + 4 * k;
    int row = ti * 64 + r, col = tj * 64 + c;
    s_t[r][c] = (float)fexp(-20.0 * (double)C[(size_t)row * 2048 + col]);
  }
  __syncthreads();
#pragma unroll
  for (int k = 0; k < 16; ++k) {
    int r = r0 + 4 * k;
    KT[(size_t)(tj * 64 + r) * 2048 + ti * 64 + c] = s_t[c][r];
  }
  if (b == 0) {
    double* z = (double*)(base + OFF_Z);
    double* scal = (double*)(base + OFF_SCAL);
    double* SzB = (double*)(base + OFF_SZB);
    for (int t = tid; t < 2048; t += 256) z[t] = 1.0;
    if (tid < 128) SzB[tid] = (tid == 0) ? 2048.0 : 0.0;
    if (tid == 0) { scal[1] = 1.0; *cnt = 0u; }
  }
}

// Fence-free device barrier. Entry __syncthreads drains every wave's vmcnt
// (compiler emits s_waitcnt vmcnt(0) before s_barrier), so all this block's
// sc1 stores are at the coherence point before the leader's arrival add.
static __device__ __forceinline__ void gsync(unsigned* cnt, unsigned target) {
  __syncthreads();
  if (threadIdx.x == 0) {
    asm volatile("s_waitcnt vmcnt(0)" ::: "memory");
    __hip_atomic_fetch_add(cnt, 1u, __ATOMIC_RELAXED, __HIP_MEMORY_SCOPE_AGENT);
    while (__hip_atomic_load(cnt, __ATOMIC_RELAXED, __HIP_MEMORY_SCOPE_AGENT) < target)
      ;
  }
  __syncthreads();
  asm volatile("" ::: "memory");
}

// One half-step, 2 rows per wave. ka/kb = this wave's two matrix rows in
// VGPRs (fp32 pairs, element j = 2*(l+64k)+{0,1}).
static __device__ __forceinline__ void half_phase(
    const float2 (&ka)[16], const float2 (&kb)[16], const double* __restrict__ vin,
    double* __restrict__ vout, const double* __restrict__ SpIn, double* __restrict__ SpOut,
    const double* padIn, double* padOut, double* s_v, double* s_w16,
    int tid, int b, int wv, int l, int i0, int i1) {
  // stage vin: 4 coalesced 8B agent-scope (sc1) loads per thread
  s_v[tid] = aload(vin + tid);
  s_v[tid + 512] = aload(vin + tid + 512);
  s_v[tid + 1024] = aload(vin + tid + 1024);
  s_v[tid + 1536] = aload(vin + tid + 1536);
  double pads = aload(padIn);
  __syncthreads();
  const double2* vz = (const double2*)s_v;
  double a0 = 0, a1 = 0, b0 = 0, b1 = 0;
#pragma unroll
  for (int k = 0; k < 16; ++k) {
    double2 p = vz[l + 64 * k];  // dense 16B/lane, conflict-free
    a0 = fma((double)ka[k].x, p.x, a0);
    a1 = fma((double)ka[k].y, p.y, a1);
    b0 = fma((double)kb[k].x, p.x, b0);
    b1 = fma((double)kb[k].y, p.y, b1);
  }
  double accA = a0 + a1, accB = b0 + b1;
#pragma unroll
  for (int off = 32; off; off >>= 1) {
    accA += __shfl_xor(accA, off, 64);
    accB += __shfl_xor(accB, off, 64);
  }
  double wiA = INV_N / (accA + 2048.0 * pads);
  double wiB = INV_N / (accB + 2048.0 * pads);
  if (l == 0) {
    astore(&vout[i0], wiA); s_w16[wv] = wiA;
    astore(&vout[i1], wiB); s_w16[8 + wv] = wiB;
  }
  if (b == 0 && wv == 7) {  // pad dual for the NEXT half-step (from prev partials)
    double tp = aload(SpIn + l) + aload(SpIn + l + 64);
#pragma unroll
    for (int off = 32; off; off >>= 1) tp += __shfl_xor(tp, off, 64);
    if (l == 0) astore(padOut, INV_N / (tp + 2048.0 * pads));
  }
  __syncthreads();
  if (tid == 0) {
    double s = 0;
#pragma unroll
    for (int q = 0; q < 16; ++q) s += s_w16[q];
    astore(&SpOut[b], s);
  }
}

// Persistent kernel: reg-load -> 100 half-steps (fence-free barriers) -> epilogue.
__global__ __launch_bounds__(512, 2) void k_loop(const float* __restrict__ C, char* base,
                                                 unsigned* __restrict__ cnt) {
  double* w = (double*)(base + OFF_W);
  double* z = (double*)(base + OFF_Z);
  double* scal = (double*)(base + OFF_SCAL);
  double* SwB = (double*)(base + OFF_SWB);
  double* SzB = (double*)(base + OFF_SZB);
  const float* KT = (const float*)(base + OFF_KT);
  float* out = (float*)base;

  __shared__ double s_v[2048];
  __shared__ float s_valf[2048];
  __shared__ double s_w16[16];

  const int tid = threadIdx.x, b = blockIdx.x;
  const int wv = tid >> 6, l = tid & 63;
  const int i0 = b * 16 + wv, i1 = i0 + 8;

  // ---- pin K rows (from C, fp64 exp -> fp32) and K cols (from KT) in VGPRs ----
  float2 kra[16], krb[16], kca[16], kcb[16];
  {
    const float2* cA = (const float2*)(C + (size_t)i0 * 2048);
    const float2* cB = (const float2*)(C + (size_t)i1 * 2048);
    const float2* tA = (const float2*)(KT + (size_t)i0 * 2048);
    const float2* tB = (const float2*)(KT + (size_t)i1 * 2048);
#pragma unroll
    for (int k = 0; k < 16; ++k) {
      float2 ca = cA[l + 64 * k], cb = cB[l + 64 * k];
      kra[k].x = (float)fexp(-20.0 * (double)ca.x);
      kra[k].y = (float)fexp(-20.0 * (double)ca.y);
      krb[k].x = (float)fexp(-20.0 * (double)cb.x);
      krb[k].y = (float)fexp(-20.0 * (double)cb.y);
      kca[k] = tA[l + 64 * k];
      kcb[k] = tB[l + 64 * k];
    }
  }

  unsigned bar = 0;
  for (int t = 0; t < 50; ++t) {
    // row update: w from z (pad: wpad from sum(z), consumed next half-step)
    half_phase(kra, krb, z, w, SzB, SwB, scal + 1, scal + 0, s_v, s_w16, tid, b, wv, l, i0, i1);
    ++bar; gsync(cnt, NBLK * bar);
    // col update: z from w (pad: zpad from sum(w))
    half_phase(kca, kcb, w, z, SwB, SzB, scal + 0, scal + 1, s_v, s_w16, tid, b, wv, l, i0, i1);
    ++bar; gsync(cnt, NBLK * bar);
  }

  // ---- epilogue: stage final state, barrier, then materialize all 4096 rows ----
  {
    double za = aload(z + 2 * tid), zb = aload(z + 2 * tid + 1);
    double zc = aload(z + 1024 + 2 * tid), zd = aload(z + 1024 + 2 * tid + 1);
    s_v[2 * tid] = za; s_v[2 * tid + 1] = zb;
    s_v[1024 + 2 * tid] = zc; s_v[1024 + 2 * tid + 1] = zd;
    double wpad = aload(&scal[0]);
    double zpad = aload(&scal[1]);
    if (tid < 16) s_w16[tid] = aload(&w[b * 16 + tid]);
    // bottom-row pattern (identical for every row 2048..4095)
    s_valf[2 * tid] = (float)(4096.0 * fmin(wpad * za, 1.0));
    s_valf[2 * tid + 1] = (float)(4096.0 * fmin(wpad * zb, 1.0));
    s_valf[1024 + 2 * tid] = (float)(4096.0 * fmin(wpad * zc, 1.0));
    s_valf[1024 + 2 * tid + 1] = (float)(4096.0 * fmin(wpad * zd, 1.0));
    // Barrier: every block finished reading w/z/scal from global before
    // rows 4093..4095 (which alias them) get overwritten below.
    ++bar; gsync(cnt, NBLK * bar);

    const double2* vz = (const double2*)s_v;
    float cf = (float)(4096.0 * fmin(wpad * zpad, 1.0));
    float4 fcb; fcb.x = cf; fcb.y = cf; fcb.z = cf; fcb.w = cf;

#pragma unroll
    for (int rr = 0; rr < 2; ++rr) {
      const int i = rr ? i1 : i0;
      double wi = s_w16[rr ? (8 + wv) : wv];
      // top row i: left = 4096*min(w_i z_j exp(-20C_ij),1), right = const
      const float2* crow = (const float2*)(C + (size_t)i * 2048);
      float2* orow2 = (float2*)(out + (size_t)i * 4096);
#pragma unroll 4
      for (int k = 0; k < 16; ++k) {
        float2 cv = crow[l + 64 * k];
        double2 p = vz[l + 64 * k];
        float2 f;
        f.x = (float)(4096.0 * fmin(wi * p.x * fexp(-20.0 * (double)cv.x), 1.0));
        f.y = (float)(4096.0 * fmin(wi * p.y * fexp(-20.0 * (double)cv.y), 1.0));
        orow2[l + 64 * k] = f;
      }
      float cr = (float)(4096.0 * fmin(wi * zpad, 1.0));
      float4 fct; fct.x = cr; fct.y = cr; fct.z = cr; fct.w = cr;
      float* orow = out + (size_t)i * 4096;
#pragma unroll
      for (int k = 0; k < 8; ++k) ((float4*)(orow + 2048))[l + 64 * k] = fct;
      // bottom row 2048+i (covers 2048..4095 incl. the state-aliasing tail)
      float* brow = out + (size_t)(2048 + i) * 4096;
#pragma unroll
      for (int k = 0; k < 8; ++k) ((float4*)brow)[l + 64 * k] = ((const float4*)s_valf)[l + 64 * k];
#pragma unroll
      for (int k = 0; k < 8; ++k) ((float4*)(brow + 2048))[l + 64 * k] = fcb;
    }
  }
}

extern "C" void kernel_launch(void* const* d_in, const int* in_sizes, int n_in,
                              void* d_out, int out_size, void* d_ws, size_t ws_size,
                              hipStream_t stream) {
  (void)in_sizes; (void)n_in; (void)out_size;
  const float* C = (const float*)d_in[0];
  char* base = (char*)d_out;
  unsigned* cnt = (d_ws != nullptr && ws_size >= 64) ? (unsigned*)d_ws
                                                     : (unsigned*)(base + OFF_CNT);
  k_build<<<1024, 256, 0, stream>>>(C, base, cnt);
  k_loop<<<128, 512, 0, stream>>>(C, base, cnt);
}

// Round 3
// 708.634 us; speedup vs baseline: 1.6665x; 1.2045x over previous
//
#include <hip/hip_runtime.h>

// Sinkhorn, fully fused: 2 dispatches.
//   k_build: KT = exp(-20*C)^T (fp32, LDS tile transpose) + state init.
//   k_loop : persistent kernel, 128 blocks x 512 thr. Each wave owns TWO rows
//            and TWO cols of K in VGPRs (whole 33 MB matrix in the register
//            file across 2048 waves) -> zero matrix traffic in the loop.
// Device-wide sync: CONTENTION-FREE flag barrier. Arrival = one relaxed
// agent-scope store per block to its OWN flag (128 flags, 64B-strided; no
// RMW serialization -- the single-counter fetch_add queue was ~6us/barrier).
// Detection = wave 0 polls all 128 flags in parallel (2 per lane) + __all
// ballot: one IF round-trip, independent of block count. All cross-block
// data (w/z/SpB/pads/flags) uses relaxed agent-scope atomics (sc0/sc1
// cache-bypass straight to the coherent Infinity Cache; no L2 maintenance).
// Math identical (absmax ~7.6e-6):
//   z_j = e^{v_j/eps}, w_i = e^{u_i/eps}, K = exp(-20C) fp32, state fp64.
//   row:  w_i = (1/4096)/(sum_j K_ij z_j + 2048*zpad)
//   col:  z_j = (1/4096)/(sum_i K^T_ji w_i + 2048*wpad)
//   pads: wpad = (1/4096)/(sum_j z_j + 2048*zpad); zpad symmetric.

#define INV_N (1.0 / 4096.0)
#define NBLK 128

// ---- scratch layout inside d_out (67,108,864 bytes) ----
#define OFF_KT 0UL            // KT fp32 2048x2048 -> overwritten by out rows in epilogue
#define OFF_W 67059712UL      // w: 2048 fp64 = out row 4093
#define OFF_Z 67076096UL      // z: 2048 fp64 = out row 4094
#define OFF_SCAL 67092480UL   // scal[0]=wpad scal[1]=zpad (row 4095; epilogue-overwritten last)
#define OFF_SWB 67092544UL    // 128 fp64 per-block sums of w
#define OFF_SZB 67094592UL    // 128 fp64 per-block sums of z
#define OFF_FLAGS 67096640UL  // 128 u32 barrier flags, 64B stride (8 KB, row-4095 spare)

static __device__ __forceinline__ double aload(const double* p) {
  return __hip_atomic_load(p, __ATOMIC_RELAXED, __HIP_MEMORY_SCOPE_AGENT);
}
static __device__ __forceinline__ void astore(double* p, double v) {
  __hip_atomic_store(p, v, __ATOMIC_RELAXED, __HIP_MEMORY_SCOPE_AGENT);
}

// fp64 exp (rel err ~3e-13 on [-20,0]).
static __device__ __forceinline__ double fexp(double x) {
  double t = x * 1.4426950408889634074;
  double n = rint(t);
  double r = fma(n, -0.69314718055994530942, x);
  double p = 2.7557319223985890653e-7;
  p = fma(p, r, 2.7557319223985890653e-6);
  p = fma(p, r, 2.4801587301587301587e-5);
  p = fma(p, r, 1.9841269841269841270e-4);
  p = fma(p, r, 1.3888888888888888889e-3);
  p = fma(p, r, 8.3333333333333333333e-3);
  p = fma(p, r, 4.1666666666666666667e-2);
  p = fma(p, r, 1.6666666666666666667e-1);
  p = fma(p, r, 0.5);
  p = fma(p, r, 1.0);
  p = fma(p, r, 1.0);
  long long bits = ((long long)(1023 + (int)n)) << 52;
  return p * __longlong_as_double(bits);
}

// Build KT (fp32, LDS tile transpose) + init state + zero barrier flags.
// 1024 blocks x 256 thr; one 64x64 tile per block.
__global__ __launch_bounds__(256) void k_build(const float* __restrict__ C, char* base) {
  float* KT = (float*)(base + OFF_KT);
  __shared__ float s_t[64][65];
  int b = blockIdx.x, tid = threadIdx.x;
  int ti = b >> 5, tj = b & 31;
  int r0 = tid >> 6, c = tid & 63;
#pragma unroll
  for (int k = 0; k < 16; ++k) {
    int r = r0 + 4 * k;
    int row = ti * 64 + r, col = tj * 64 + c;
    s_t[r][c] = (float)fexp(-20.0 * (double)C[(size_t)row * 2048 + col]);
  }
  __syncthreads();
#pragma unroll
  for (int k = 0; k < 16; ++k) {
    int r = r0 + 4 * k;
    KT[(size_t)(tj * 64 + r) * 2048 + ti * 64 + c] = s_t[c][r];
  }
  if (b == 0) {
    double* z = (double*)(base + OFF_Z);
    double* scal = (double*)(base + OFF_SCAL);
    double* SzB = (double*)(base + OFF_SZB);
    unsigned* flags = (unsigned*)(base + OFF_FLAGS);
    for (int t = tid; t < 2048; t += 256) z[t] = 1.0;
    if (tid < 128) {
      SzB[tid] = (tid == 0) ? 2048.0 : 0.0;
      flags[tid * 16] = 0u;
    }
    if (tid == 0) scal[1] = 1.0;
  }
}

// Contention-free device barrier. Caller guarantees a __syncthreads has
// already drained all waves' sc1 stores (compiler emits s_waitcnt vmcnt(0)
// before s_barrier). tid0's own trailing store (SpOut) is drained by the
// explicit vmcnt(0) before the flag store.
static __device__ __forceinline__ void gsync(unsigned* flags, unsigned bar, int tid, int b) {
  if (tid == 0) {
    asm volatile("s_waitcnt vmcnt(0)" ::: "memory");
    __hip_atomic_store(flags + b * 16, bar, __ATOMIC_RELAXED, __HIP_MEMORY_SCOPE_AGENT);
  }
  if (tid < 64) {  // wave 0: poll all 128 flags, 2 per lane
    const unsigned* fa = flags + tid * 16;
    const unsigned* fb = flags + (tid + 64) * 16;
    for (;;) {
      unsigned x = __hip_atomic_load(fa, __ATOMIC_RELAXED, __HIP_MEMORY_SCOPE_AGENT);
      unsigned y = __hip_atomic_load(fb, __ATOMIC_RELAXED, __HIP_MEMORY_SCOPE_AGENT);
      if (__all((x >= bar) && (y >= bar))) break;
    }
  }
  __syncthreads();
  asm volatile("" ::: "memory");
}

// One half-step, 2 rows per wave. ka/kb = this wave's two matrix rows in
// VGPRs (fp32 pairs, element j = 2*(l+64k)+{0,1}). Ends with __syncthreads
// (drains all stores) + tid0's SpOut store -- gsync follows immediately.
static __device__ __forceinline__ void half_phase(
    const float2 (&ka)[16], const float2 (&kb)[16], const double* __restrict__ vin,
    double* __restrict__ vout, const double* __restrict__ SpIn, double* __restrict__ SpOut,
    const double* padIn, double* padOut, double* s_v, double* s_w16,
    int tid, int b, int wv, int l, int i0, int i1) {
  // stage vin: 4 coalesced 8B agent-scope (sc1) loads per thread
  s_v[tid] = aload(vin + tid);
  s_v[tid + 512] = aload(vin + tid + 512);
  s_v[tid + 1024] = aload(vin + tid + 1024);
  s_v[tid + 1536] = aload(vin + tid + 1536);
  double pads = aload(padIn);
  __syncthreads();
  const double2* vz = (const double2*)s_v;
  double a0 = 0, a1 = 0, b0 = 0, b1 = 0;
#pragma unroll
  for (int k = 0; k < 16; ++k) {
    double2 p = vz[l + 64 * k];  // dense 16B/lane, conflict-free
    a0 = fma((double)ka[k].x, p.x, a0);
    a1 = fma((double)ka[k].y, p.y, a1);
    b0 = fma((double)kb[k].x, p.x, b0);
    b1 = fma((double)kb[k].y, p.y, b1);
  }
  double accA = a0 + a1, accB = b0 + b1;
#pragma unroll
  for (int off = 32; off; off >>= 1) {
    accA += __shfl_xor(accA, off, 64);
    accB += __shfl_xor(accB, off, 64);
  }
  double wiA = INV_N / (accA + 2048.0 * pads);
  double wiB = INV_N / (accB + 2048.0 * pads);
  if (l == 0) {
    astore(&vout[i0], wiA); s_w16[wv] = wiA;
    astore(&vout[i1], wiB); s_w16[8 + wv] = wiB;
  }
  if (b == 0 && wv == 7) {  // pad dual for the NEXT half-step (from prev partials)
    double tp = aload(SpIn + l) + aload(SpIn + l + 64);
#pragma unroll
    for (int off = 32; off; off >>= 1) tp += __shfl_xor(tp, off, 64);
    if (l == 0) astore(padOut, INV_N / (tp + 2048.0 * pads));
  }
  __syncthreads();  // drains every wave's w/pad stores (vmcnt 0 before s_barrier)
  if (tid == 0) {
    double s = 0;
#pragma unroll
    for (int q = 0; q < 16; ++q) s += s_w16[q];
    astore(&SpOut[b], s);
  }
}

// Persistent kernel: reg-load -> 100 half-steps (flag barriers) -> epilogue.
__global__ __launch_bounds__(512, 2) void k_loop(const float* __restrict__ C, char* base) {
  double* w = (double*)(base + OFF_W);
  double* z = (double*)(base + OFF_Z);
  double* scal = (double*)(base + OFF_SCAL);
  double* SwB = (double*)(base + OFF_SWB);
  double* SzB = (double*)(base + OFF_SZB);
  unsigned* flags = (unsigned*)(base + OFF_FLAGS);
  const float* KT = (const float*)(base + OFF_KT);
  float* out = (float*)base;

  __shared__ double s_v[2048];
  __shared__ float s_valf[2048];
  __shared__ double s_w16[16];

  const int tid = threadIdx.x, b = blockIdx.x;
  const int wv = tid >> 6, l = tid & 63;
  const int i0 = b * 16 + wv, i1 = i0 + 8;

  // ---- pin K rows (from C, fp64 exp -> fp32) and K cols (from KT) in VGPRs ----
  float2 kra[16], krb[16], kca[16], kcb[16];
  {
    const float2* cA = (const float2*)(C + (size_t)i0 * 2048);
    const float2* cB = (const float2*)(C + (size_t)i1 * 2048);
    const float2* tA = (const float2*)(KT + (size_t)i0 * 2048);
    const float2* tB = (const float2*)(KT + (size_t)i1 * 2048);
#pragma unroll
    for (int k = 0; k < 16; ++k) {
      float2 ca = cA[l + 64 * k], cb = cB[l + 64 * k];
      kra[k].x = (float)fexp(-20.0 * (double)ca.x);
      kra[k].y = (float)fexp(-20.0 * (double)ca.y);
      krb[k].x = (float)fexp(-20.0 * (double)cb.x);
      krb[k].y = (float)fexp(-20.0 * (double)cb.y);
      kca[k] = tA[l + 64 * k];
      kcb[k] = tB[l + 64 * k];
    }
  }

  unsigned bar = 0;
  for (int t = 0; t < 50; ++t) {
    // row update: w from z (pad: wpad from sum(z), consumed next half-step)
    half_phase(kra, krb, z, w, SzB, SwB, scal + 1, scal + 0, s_v, s_w16, tid, b, wv, l, i0, i1);
    ++bar; gsync(flags, bar, tid, b);
    // col update: z from w (pad: zpad from sum(w))
    half_phase(kca, kcb, w, z, SwB, SzB, scal + 0, scal + 1, s_v, s_w16, tid, b, wv, l, i0, i1);
    ++bar; gsync(flags, bar, tid, b);
  }

  // ---- epilogue: stage final state, barrier, then materialize all 4096 rows ----
  {
    double za = aload(z + 2 * tid), zb = aload(z + 2 * tid + 1);
    double zc = aload(z + 1024 + 2 * tid), zd = aload(z + 1024 + 2 * tid + 1);
    s_v[2 * tid] = za; s_v[2 * tid + 1] = zb;
    s_v[1024 + 2 * tid] = zc; s_v[1024 + 2 * tid + 1] = zd;
    double wpad = aload(&scal[0]);
    double zpad = aload(&scal[1]);
    if (tid < 16) s_w16[tid] = aload(&w[b * 16 + tid]);
    // bottom-row pattern (identical for every row 2048..4095)
    s_valf[2 * tid] = (float)(4096.0 * fmin(wpad * za, 1.0));
    s_valf[2 * tid + 1] = (float)(4096.0 * fmin(wpad * zb, 1.0));
    s_valf[1024 + 2 * tid] = (float)(4096.0 * fmin(wpad * zc, 1.0));
    s_valf[1024 + 2 * tid + 1] = (float)(4096.0 * fmin(wpad * zd, 1.0));
    // Barrier: every block finished reading w/z/scal from global before the
    // state-aliasing rows 4093..4095 (and the flag region itself) are
    // overwritten. Overwrites only happen after a full 128-flag detection,
    // so no block can still depend on this data; late stale polls read
    // large positive float bit-patterns (>= bar) -> no deadlock.
    __syncthreads();
    ++bar; gsync(flags, bar, tid, b);

    const double2* vz = (const double2*)s_v;
    float cf = (float)(4096.0 * fmin(wpad * zpad, 1.0));
    float4 fcb; fcb.x = cf; fcb.y = cf; fcb.z = cf; fcb.w = cf;

#pragma unroll
    for (int rr = 0; rr < 2; ++rr) {
      const int i = rr ? i1 : i0;
      double wi = s_w16[rr ? (8 + wv) : wv];
      // top row i: left = 4096*min(w_i z_j exp(-20C_ij),1), right = const
      const float2* crow = (const float2*)(C + (size_t)i * 2048);
      float2* orow2 = (float2*)(out + (size_t)i * 4096);
#pragma unroll 4
      for (int k = 0; k < 16; ++k) {
        float2 cv = crow[l + 64 * k];
        double2 p = vz[l + 64 * k];
        float2 f;
        f.x = (float)(4096.0 * fmin(wi * p.x * fexp(-20.0 * (double)cv.x), 1.0));
        f.y = (float)(4096.0 * fmin(wi * p.y * fexp(-20.0 * (double)cv.y), 1.0));
        orow2[l + 64 * k] = f;
      }
      float cr = (float)(4096.0 * fmin(wi * zpad, 1.0));
      float4 fct; fct.x = cr; fct.y = cr; fct.z = cr; fct.w = cr;
      float* orow = out + (size_t)i * 4096;
#pragma unroll
      for (int k = 0; k < 8; ++k) ((float4*)(orow + 2048))[l + 64 * k] = fct;
      // bottom row 2048+i (covers 2048..4095 incl. the state-aliasing tail)
      float* brow = out + (size_t)(2048 + i) * 4096;
#pragma unroll
      for (int k = 0; k < 8; ++k) ((float4*)brow)[l + 64 * k] = ((const float4*)s_valf)[l + 64 * k];
#pragma unroll
      for (int k = 0; k < 8; ++k) ((float4*)(brow + 2048))[l + 64 * k] = fcb;
    }
  }
}

extern "C" void kernel_launch(void* const* d_in, const int* in_sizes, int n_in,
                              void* d_out, int out_size, void* d_ws, size_t ws_size,
                              hipStream_t stream) {
  (void)in_sizes; (void)n_in; (void)out_size; (void)d_ws; (void)ws_size;
  const float* C = (const float*)d_in[0];
  char* base = (char*)d_out;
  k_build<<<1024, 256, 0, stream>>>(C, base);
  k_loop<<<128, 512, 0, stream>>>(C, base);
}

// Round 4
// 655.454 us; speedup vs baseline: 1.8018x; 1.0811x over previous
//
#include <hip/hip_runtime.h>

// Sinkhorn, fully fused, BARRIER-FREE loop via data-as-flag dataflow.
//   k_build: KT = exp(-20*C)^T (fp32) + zero 101 iterate slots + pads + flags.
//   k_loop : persistent, 256 blocks x 512 thr (1 per CU by capacity). Each
//            wave owns ONE row and ONE col of K in VGPRs (64 regs). Each
//            half-step t writes its output vector to a FRESH pre-zeroed slot
//            V[t+1]; since all iterates are strictly positive, consumers
//            poll the data itself (relaxed agent-scope loads, zero = not
//            ready). Sync and data movement are the SAME IF round trip --
//            no barrier, no fences, no partial-sum arrays (block0/wave0
//            computes sum(vin) from its staged LDS copy). One legacy flag
//            barrier guards the epilogue overwriting the slot region.
// Recurrence (identical math, absmax ~7.6e-6):
//   V[0]=1, P[0]=1;  half-step t: out_i = (1/4096)/(sum_j K._ij V[t]_j + 2048*P[t])
//   P[t+1] = (1/4096)/(sum(V[t]) + 2048*P[t]);  K. = K row-form (t even) / K^T (t odd)
//   w=V[99], wpad=P[99], z=V[100], zpad=P[100].

#define INV_N (1.0 / 4096.0)

// ---- scratch layout inside d_out (67,108,864 bytes) ----
#define OFF_KT 0UL            // KT fp32 2048x2048 (rows 0..1023 of out)
#define OFF_V 16777216UL      // V[t] = OFF_V + t*16384, t=0..100 (2048 fp64 each)
#define OFF_P 18432000UL      // P[t] = OFF_P + t*64 (fp64, 64B stride)
#define OFF_FLAGS 67096640UL  // 256 u32 epilogue flags, 32B stride (row-4095 spare)

static __device__ __forceinline__ double aload(const double* p) {
  return __hip_atomic_load(p, __ATOMIC_RELAXED, __HIP_MEMORY_SCOPE_AGENT);
}
static __device__ __forceinline__ void astore(double* p, double v) {
  __hip_atomic_store(p, v, __ATOMIC_RELAXED, __HIP_MEMORY_SCOPE_AGENT);
}

// fp64 exp (rel err ~3e-13 on [-20,0]).
static __device__ __forceinline__ double fexp(double x) {
  double t = x * 1.4426950408889634074;
  double n = rint(t);
  double r = fma(n, -0.69314718055994530942, x);
  double p = 2.7557319223985890653e-7;
  p = fma(p, r, 2.7557319223985890653e-6);
  p = fma(p, r, 2.4801587301587301587e-5);
  p = fma(p, r, 1.9841269841269841270e-4);
  p = fma(p, r, 1.3888888888888888889e-3);
  p = fma(p, r, 8.3333333333333333333e-3);
  p = fma(p, r, 4.1666666666666666667e-2);
  p = fma(p, r, 1.6666666666666666667e-1);
  p = fma(p, r, 0.5);
  p = fma(p, r, 1.0);
  p = fma(p, r, 1.0);
  long long bits = ((long long)(1023 + (int)n)) << 52;
  return p * __longlong_as_double(bits);
}

// Build KT (fp32, LDS tile transpose) + init slots/pads/flags.
// 1024 blocks x 256 thr; one 64x64 tile per block.
__global__ __launch_bounds__(256) void k_build(const float* __restrict__ C, char* base) {
  float* KT = (float*)(base + OFF_KT);
  __shared__ float s_t[64][65];
  int b = blockIdx.x, tid = threadIdx.x;
  int ti = b >> 5, tj = b & 31;
  int r0 = tid >> 6, c = tid & 63;
#pragma unroll
  for (int k = 0; k < 16; ++k) {
    int r = r0 + 4 * k;
    int row = ti * 64 + r, col = tj * 64 + c;
    s_t[r][c] = (float)fexp(-20.0 * (double)C[(size_t)row * 2048 + col]);
  }
  __syncthreads();
#pragma unroll
  for (int k = 0; k < 16; ++k) {
    int r = r0 + 4 * k;
    KT[(size_t)(tj * 64 + r) * 2048 + ti * 64 + c] = s_t[c][r];
  }
  // slot init: block t (t<=100) owns V[t]/P[t]; V[0]=P[0]=1, rest 0 (sentinel).
  if (b <= 100) {
    double* Vt = (double*)(base + OFF_V) + (size_t)b * 2048;
    double val = (b == 0) ? 1.0 : 0.0;
    for (int t = tid; t < 2048; t += 256) Vt[t] = val;
    if (tid == 0) ((double*)(base + OFF_P))[(size_t)b * 8] = val;
  }
  if (b == 101 && tid < 256) ((unsigned*)(base + OFF_FLAGS))[tid * 8] = 0u;
}

// One half-step. K = this wave's matrix row (fp32 pairs, j = 2*(l+64k)+{0,1}).
// Poll-stages V[t] into sv (zero = not written yet), MACs, stores V[t+1][i].
// pad_duty (block0/wave0): also computes P[t+1] from the staged copy.
static __device__ __forceinline__ void half_step(
    const float2 (&K)[16], int t, char* base, double* sv,
    int tid, int l, int i, bool pad_duty) {
  double* V = (double*)(base + OFF_V);
  const double* vin = V + (size_t)t * 2048;
  double* vout = V + (size_t)(t + 1) * 2048;
  const double* Pin = (const double*)(base + OFF_P) + (size_t)t * 8;
  double* Pout = (double*)(base + OFF_P) + (size_t)(t + 1) * 8;

  double v0 = aload(vin + tid), v1 = aload(vin + tid + 512);
  double v2 = aload(vin + tid + 1024), v3 = aload(vin + tid + 1536);
  while (v0 == 0.0) v0 = aload(vin + tid);
  while (v1 == 0.0) v1 = aload(vin + tid + 512);
  while (v2 == 0.0) v2 = aload(vin + tid + 1024);
  while (v3 == 0.0) v3 = aload(vin + tid + 1536);
  sv[tid] = v0; sv[tid + 512] = v1; sv[tid + 1024] = v2; sv[tid + 1536] = v3;
  double pads = aload(Pin);          // produced a whole half-step ago: usually ready
  while (pads == 0.0) pads = aload(Pin);
  __syncthreads();
  const double2* vz = (const double2*)sv;
  double a0 = 0, a1 = 0;
#pragma unroll
  for (int k = 0; k < 16; ++k) {
    double2 pz = vz[l + 64 * k];     // dense 16B/lane, conflict-free
    a0 = fma((double)K[k].x, pz.x, a0);
    a1 = fma((double)K[k].y, pz.y, a1);
  }
  double acc = a0 + a1;
#pragma unroll
  for (int off = 32; off; off >>= 1) acc += __shfl_xor(acc, off, 64);
  double wi = INV_N / (acc + 2048.0 * pads);
  if (l == 0) astore(vout + i, wi);  // the store IS the ready flag
  if (pad_duty) {                    // next pad from this wave's staged copy
    double ts = 0;
#pragma unroll
    for (int k = 0; k < 16; ++k) { double2 pz = vz[l + 64 * k]; ts += pz.x + pz.y; }
#pragma unroll
    for (int off = 32; off; off >>= 1) ts += __shfl_xor(ts, off, 64);
    if (l == 0) astore(Pout, INV_N / (ts + 2048.0 * pads));
  }
  // no trailing __syncthreads: sv is double-buffered by the caller
}

// Persistent kernel: reg-load -> 100 barrier-free half-steps -> epilogue.
__global__ __launch_bounds__(512, 2) void k_loop(const float* __restrict__ C, char* base) {
  const float* KT = (const float*)(base + OFF_KT);
  float* out = (float*)base;

  __shared__ double s_v[2][2048];
  __shared__ float s_valf[2048];
  __shared__ double s_w8[8];

  const int tid = threadIdx.x, b = blockIdx.x;
  const int wv = tid >> 6, l = tid & 63;
  const int i = b * 8 + wv;
  const bool pad_duty = (b == 0) && (wv == 0);

  // ---- pin K row i (from C, fp64 exp -> fp32) and K col i (from KT) ----
  float2 kr[16], kc[16];
  {
    const float2* cR = (const float2*)(C + (size_t)i * 2048);
    const float2* tR = (const float2*)(KT + (size_t)i * 2048);
#pragma unroll
    for (int k = 0; k < 16; ++k) {
      float2 cv = cR[l + 64 * k];
      kr[k].x = (float)fexp(-20.0 * (double)cv.x);
      kr[k].y = (float)fexp(-20.0 * (double)cv.y);
      kc[k] = tR[l + 64 * k];
    }
  }

  for (int t2 = 0; t2 < 50; ++t2) {
    half_step(kr, 2 * t2, base, s_v[0], tid, l, i, pad_duty);      // row: w from z
    half_step(kc, 2 * t2 + 1, base, s_v[1], tid, l, i, pad_duty);  // col: z from w
  }

  // ---- epilogue ----
  {
    const double* zf = (const double*)(base + OFF_V) + 100 * 2048;
    const double* wf = (const double*)(base + OFF_V) + 99 * 2048;
    const double* Pp = (const double*)(base + OFF_P);
    double* sv = s_v[0];
    double v0 = aload(zf + tid), v1 = aload(zf + tid + 512);
    double v2 = aload(zf + tid + 1024), v3 = aload(zf + tid + 1536);
    while (v0 == 0.0) v0 = aload(zf + tid);
    while (v1 == 0.0) v1 = aload(zf + tid + 512);
    while (v2 == 0.0) v2 = aload(zf + tid + 1024);
    while (v3 == 0.0) v3 = aload(zf + tid + 1536);
    sv[tid] = v0; sv[tid + 512] = v1; sv[tid + 1024] = v2; sv[tid + 1536] = v3;
    double wpad = aload(Pp + 99 * 8);
    while (wpad == 0.0) wpad = aload(Pp + 99 * 8);
    double zpad = aload(Pp + 100 * 8);
    while (zpad == 0.0) zpad = aload(Pp + 100 * 8);
    if (tid < 8) {
      double x = aload(wf + b * 8 + tid);
      while (x == 0.0) x = aload(wf + b * 8 + tid);
      s_w8[tid] = x;
    }
    // bottom-row pattern (identical for every row 2048..4095)
    s_valf[tid] = (float)(4096.0 * fmin(wpad * v0, 1.0));
    s_valf[tid + 512] = (float)(4096.0 * fmin(wpad * v1, 1.0));
    s_valf[tid + 1024] = (float)(4096.0 * fmin(wpad * v2, 1.0));
    s_valf[tid + 1536] = (float)(4096.0 * fmin(wpad * v3, 1.0));
    __syncthreads();  // all slot reads of this block complete

    // One-time device barrier: no block may overwrite the slot/flag regions
    // until every block has finished reading them. Late stale flag polls
    // read output-float bit patterns (positive -> >=1): no deadlock.
    unsigned* flags = (unsigned*)(base + OFF_FLAGS);
    if (tid == 0) {
      asm volatile("s_waitcnt vmcnt(0)" ::: "memory");
      __hip_atomic_store(flags + b * 8, 1u, __ATOMIC_RELAXED, __HIP_MEMORY_SCOPE_AGENT);
    }
    if (tid < 64) {  // wave 0 polls all 256 flags, 4 per lane
      for (;;) {
        unsigned x0 = __hip_atomic_load(flags + tid * 8, __ATOMIC_RELAXED, __HIP_MEMORY_SCOPE_AGENT);
        unsigned x1 = __hip_atomic_load(flags + (tid + 64) * 8, __ATOMIC_RELAXED, __HIP_MEMORY_SCOPE_AGENT);
        unsigned x2 = __hip_atomic_load(flags + (tid + 128) * 8, __ATOMIC_RELAXED, __HIP_MEMORY_SCOPE_AGENT);
        unsigned x3 = __hip_atomic_load(flags + (tid + 192) * 8, __ATOMIC_RELAXED, __HIP_MEMORY_SCOPE_AGENT);
        if (__all(x0 && x1 && x2 && x3)) break;
      }
    }
    __syncthreads();

    const double2* vz = (const double2*)sv;
    double wi = s_w8[wv];
    float cf = (float)(4096.0 * fmin(wpad * zpad, 1.0));
    float4 fcb; fcb.x = cf; fcb.y = cf; fcb.z = cf; fcb.w = cf;

    // top row i: left = 4096*min(w_i z_j exp(-20C_ij),1), right = const
    const float2* crow = (const float2*)(C + (size_t)i * 2048);
    float* orow = out + (size_t)i * 4096;
    float2* orow2 = (float2*)orow;
#pragma unroll 4
    for (int k = 0; k < 16; ++k) {
      float2 cv = crow[l + 64 * k];
      double2 pz = vz[l + 64 * k];
      float2 f;
      f.x = (float)(4096.0 * fmin(wi * pz.x * fexp(-20.0 * (double)cv.x), 1.0));
      f.y = (float)(4096.0 * fmin(wi * pz.y * fexp(-20.0 * (double)cv.y), 1.0));
      orow2[l + 64 * k] = f;
    }
    float cr = (float)(4096.0 * fmin(wi * zpad, 1.0));
    float4 fct; fct.x = cr; fct.y = cr; fct.z = cr; fct.w = cr;
#pragma unroll
    for (int k = 0; k < 8; ++k) ((float4*)(orow + 2048))[l + 64 * k] = fct;
    // bottom row 2048+i
    float* brow = out + (size_t)(2048 + i) * 4096;
#pragma unroll
    for (int k = 0; k < 8; ++k) ((float4*)brow)[l + 64 * k] = ((const float4*)s_valf)[l + 64 * k];
#pragma unroll
    for (int k = 0; k < 8; ++k) ((float4*)(brow + 2048))[l + 64 * k] = fcb;
  }
}

extern "C" void kernel_launch(void* const* d_in, const int* in_sizes, int n_in,
                              void* d_out, int out_size, void* d_ws, size_t ws_size,
                              hipStream_t stream) {
  (void)in_sizes; (void)n_in; (void)out_size; (void)d_ws; (void)ws_size;
  const float* C = (const float*)d_in[0];
  char* base = (char*)d_out;
  k_build<<<1024, 256, 0, stream>>>(C, base);
  k_loop<<<256, 512, 0, stream>>>(C, base);
}